// Round 13
// baseline (27.983 us; speedup 1.0000x reference)
//
#include <hip/hip_runtime.h>
#include <stdint.h>

#define NB 4096
#define QLEN 1024
#define NL 64
#define KLEN 32
#define NS (QLEN - KLEN + 1)   // 993
#define SLICE 1856             // u32 per row slice

typedef __attribute__((ext_vector_type(8))) _Float16 half8;
typedef __attribute__((ext_vector_type(4))) float f32x4;

union fragh { uint32_t u[4]; half8 v; };

static __device__ __forceinline__ uint32_t pkh(float a, float b) {
    return __builtin_bit_cast(uint32_t, __builtin_amdgcn_cvt_pkrtz(a, b)); // v_cvt_pkrtz_f16_f32
}
static __device__ __forceinline__ float lo16f(uint32_t w) {
    return (float)__builtin_bit_cast(_Float16, (unsigned short)(w & 0xFFFFu));
}
static __device__ __forceinline__ float hi16f(uint32_t w) {
    return (float)__builtin_bit_cast(_Float16, (unsigned short)(w >> 16));
}
static __device__ __forceinline__ uint32_t pkh_rne(float a, float b) {  // RNE f16 pair
    unsigned short ha = __builtin_bit_cast(unsigned short, (_Float16)a);
    unsigned short hb = __builtin_bit_cast(unsigned short, (_Float16)b);
    return (uint32_t)ha | ((uint32_t)hb << 16);
}

__global__ __launch_bounds__(256, 8) void shapelet_r13(
    const float* __restrict__ ts,        // [B, Q]
    const float* __restrict__ shapelets, // [L, K]
    const float* __restrict__ fc_w,      // [2, L]
    const float* __restrict__ fc_b,      // [2]
    float* __restrict__ out)             // [B, 2]
{
    // 2 row slices + feat-merge buffer; 15.9 KB -> 8 blocks/CU -> 8 waves/SIMD
    __shared__ __align__(16) uint32_t lds[2 * SLICE];
    __shared__ float lds_pm[2][2][NL];   // [row-in-block][half][feat]

    const int tid  = threadIdx.x;
    const int lane = tid & 63;
    const int wave = tid >> 6;
    const int rw   = wave >> 1;          // row-in-block (0,1)
    const int h    = wave & 1;           // half of the row this wave owns
    const int col  = lane & 15;
    const int kg   = lane >> 4;
    const int row  = blockIdx.x * 2 + rw;

    uint32_t* pkE = lds + rw * SLICE;                      // [528]
    uint32_t* pkO = pkE + 528;                             // [528]
    uint32_t* nwh = pkO + 528;                             // [512]
    float*    s4  = reinterpret_cast<float*>(nwh + 512);   // [264]

    // --- pass 1: this wave packs chunks c = 2h, 2h+1 of its row ---
    const float* rowp = ts + (size_t)row * QLEN;
    float4 v0, v1;
    {
        v0 = reinterpret_cast<const float4*>(rowp)[64 * (2 * h + 0) + lane];
        v1 = reinterpret_cast<const float4*>(rowp)[64 * (2 * h + 1) + lane];
        const int pa = 256 * (2 * h + 0) + 4 * lane + 4;
        const int pb = 256 * (2 * h + 1) + 4 * lane + 4;
        float xa = rowp[pa];                              // pa < 1024 always
        float xb = (pb < QLEN) ? rowp[pb] : 0.0f;
        uint2 pe0 = { pkh(v0.x, v0.y), pkh(v0.z, v0.w) };
        uint2 po0 = { pkh(v0.y, v0.z), pkh(v0.w, xa) };
        uint2 pe1 = { pkh(v1.x, v1.y), pkh(v1.z, v1.w) };
        uint2 po1 = { pkh(v1.y, v1.z), pkh(v1.w, xb) };
        reinterpret_cast<uint2*>(pkE)[64 * (2 * h + 0) + lane] = pe0;
        reinterpret_cast<uint2*>(pkO)[64 * (2 * h + 0) + lane] = po0;
        reinterpret_cast<uint2*>(pkE)[64 * (2 * h + 1) + lane] = pe1;
        reinterpret_cast<uint2*>(pkO)[64 * (2 * h + 1) + lane] = po1;
        s4[64 * (2 * h + 0) + lane] =
            fmaf(v0.x, v0.x, fmaf(v0.y, v0.y, fmaf(v0.z, v0.z, v0.w * v0.w)));
        s4[64 * (2 * h + 1) + lane] =
            fmaf(v1.x, v1.x, fmaf(v1.y, v1.y, fmaf(v1.z, v1.z, v1.w * v1.w)));
    }
    if (h == 1 && lane < 16) { pkE[512 + lane] = 0u; pkO[512 + lane] = 0u; }
    if (h == 1 && lane < 8)  s4[256 + lane] = 0.0f;

    // --- B fragments (fp16 RTZ) + exact fp32 ssq partials ---
    fragh Bh[4];
    float ssq[4];
    #pragma unroll
    for (int lt = 0; lt < 4; ++lt) {
        const float* sp = shapelets + (lt * 16 + col) * KLEN + kg * 8;
        float4 f0 = *reinterpret_cast<const float4*>(sp);
        float4 f1 = *reinterpret_cast<const float4*>(sp + 4);
        Bh[lt].u[0] = pkh(f0.x, f0.y);
        Bh[lt].u[1] = pkh(f0.z, f0.w);
        Bh[lt].u[2] = pkh(f1.x, f1.y);
        Bh[lt].u[3] = pkh(f1.z, f1.w);
        float s = f0.x * f0.x;
        s = fmaf(f0.y, f0.y, s); s = fmaf(f0.z, f0.z, s); s = fmaf(f0.w, f0.w, s);
        s = fmaf(f1.x, f1.x, s); s = fmaf(f1.y, f1.y, s);
        s = fmaf(f1.z, f1.z, s); s = fmaf(f1.w, f1.w, s);
        ssq[lt] = s;   // kg-partial; reduced in epilogue
    }

    __syncthreads();   // all pack writes visible to all waves of the block

    // --- pass 2: win_sq for own chunks (may read across chunk boundary) ---
    #pragma unroll
    for (int cc = 0; cc < 2; ++cc) {
        const int q  = 64 * (2 * h + cc) + lane;
        const float4 vv = cc ? v1 : v0;
        float s_[8];
        #pragma unroll
        for (int j = 0; j < 8; ++j) s_[j] = s4[q + j];
        float w0 = ((s_[0] + s_[1]) + (s_[2] + s_[3])) + ((s_[4] + s_[5]) + (s_[6] + s_[7]));
        uint32_t cw0 = pkE[2 * (q + 8)];
        uint32_t cw1 = pkE[2 * (q + 8) + 1];
        float x32 = lo16f(cw0), x33 = hi16f(cw0), x34 = lo16f(cw1);
        float w1 = fmaf(x32, x32, fmaf(-vv.x, vv.x, w0));
        float w2 = fmaf(x33, x33, fmaf(-vv.y, vv.y, w1));
        float w3 = fmaf(x34, x34, fmaf(-vv.z, vv.z, w2));
        const int p0 = 4 * q;
        float c0 = (p0 + 0 < NS) ? -0.5f * w0 : -60000.0f;
        float c1 = (p0 + 1 < NS) ? -0.5f * w1 : -60000.0f;
        float c2 = (p0 + 2 < NS) ? -0.5f * w2 : -60000.0f;
        float c3 = (p0 + 3 < NS) ? -0.5f * w3 : -60000.0f;
        const int qq = p0 & 31;
        const int W = ((p0 >> 5) << 4) + (((qq & 15) >> 2) << 2) + ((qq >> 4) << 1);
        uint2 hw = { pkh_rne(c0, c1), pkh_rne(c2, c3) };
        *reinterpret_cast<uint2*>(&nwh[W]) = hw;
    }

    __builtin_amdgcn_wave_barrier();   // order own pass-2 stores before main reads

    // --- main loop: 16 tile-pairs (own half), r12's exact iteration body ---
    float rmax[4][4];
    #pragma unroll
    for (int lt = 0; lt < 4; ++lt)
        #pragma unroll
        for (int e = 0; e < 4; ++e) rmax[lt][e] = -3.0e38f;

    const int par = col & 1;
    const uint32_t* apk = (par ? pkO : pkE) + (((col - par) >> 1) + kg * 4) + 256 * h;
    const uint32_t* nwp = nwh + 256 * h + 4 * kg;

    #pragma unroll 2
    for (int i = 0; i < 16; ++i) {
        const uint32_t* ap = apk + 16 * i;
        fragh Aa, Ab;
        #pragma unroll
        for (int j = 0; j < 4; ++j) Aa.u[j] = ap[j];
        #pragma unroll
        for (int j = 0; j < 4; ++j) Ab.u[j] = ap[8 + j];

        uint4 nw = *reinterpret_cast<const uint4*>(nwp + 16 * i);
        f32x4 ia, ib;
        ia[0] = lo16f(nw.x); ia[1] = hi16f(nw.x);
        ia[2] = lo16f(nw.y); ia[3] = hi16f(nw.y);
        ib[0] = lo16f(nw.z); ib[1] = hi16f(nw.z);
        ib[2] = lo16f(nw.w); ib[3] = hi16f(nw.w);

        #pragma unroll
        for (int lt = 0; lt < 4; ++lt) {
            f32x4 aa = __builtin_amdgcn_mfma_f32_16x16x32_f16(Aa.v, Bh[lt].v, ia, 0, 0, 0);
            f32x4 ab = __builtin_amdgcn_mfma_f32_16x16x32_f16(Ab.v, Bh[lt].v, ib, 0, 0, 0);
            #pragma unroll
            for (int e = 0; e < 4; ++e)
                rmax[lt][e] = fmaxf(fmaxf(aa[e], ab[e]), rmax[lt][e]);  // v_max3_f32
        }
    }

    // --- per-wave reduce -> pm[rw][h][feat] ---
    #pragma unroll
    for (int lt = 0; lt < 4; ++lt) {
        float m = fmaxf(fmaxf(rmax[lt][0], rmax[lt][1]),
                        fmaxf(rmax[lt][2], rmax[lt][3]));
        m = fmaxf(m, __shfl_xor(m, 16, 64));
        m = fmaxf(m, __shfl_xor(m, 32, 64));
        if (kg == 0) lds_pm[rw][h][lt * 16 + col] = m;
    }
    __syncthreads();

    // --- merge halves + fc: wave h==0 of each row finishes ---
    if (h == 0) {
        float p0v = 0.0f, p1v = 0.0f;
        #pragma unroll
        for (int lt = 0; lt < 4; ++lt) {
            const int ft = lt * 16 + col;
            float m = fmaxf(lds_pm[rw][0][ft], lds_pm[rw][1][ft]);
            float sq = ssq[lt];
            sq += __shfl_xor(sq, 16, 64);
            sq += __shfl_xor(sq, 32, 64);             // exact ssq, all lanes
            float f = (sq - 2.0f * m) * (1.0f / (float)KLEN);   // min dist
            p0v = fmaf(f, fc_w[ft], p0v);
            p1v = fmaf(f, fc_w[NL + ft], p1v);
        }
        #pragma unroll
        for (int off = 1; off <= 8; off <<= 1) {
            p0v += __shfl_xor(p0v, off, 64);
            p1v += __shfl_xor(p1v, off, 64);
        }
        if (lane == 0) {
            out[(size_t)row * 2 + 0] = p0v + fc_b[0];
            out[(size_t)row * 2 + 1] = p1v + fc_b[1];
        }
    }
}

extern "C" void kernel_launch(void* const* d_in, const int* in_sizes, int n_in,
                              void* d_out, int out_size, void* d_ws, size_t ws_size,
                              hipStream_t stream) {
    const float* ts        = (const float*)d_in[0];
    const float* shapelets = (const float*)d_in[1];
    const float* fc_w      = (const float*)d_in[2];
    const float* fc_b      = (const float*)d_in[3];
    float* out = (float*)d_out;

    shapelet_r13<<<NB / 2, 256, 0, stream>>>(ts, shapelets, fc_w, fc_b, out);
}